// Round 6
// baseline (982.535 us; speedup 1.0000x reference)
//
#include <hip/hip_runtime.h>
#include <stdint.h>

// Problem constants
#define BB   8
#define NH   8
#define QQ   100
#define HWK  16384
#define DM   256
#define HD   32
#define QP   112      // Q padded to 7 * 16
#define MT   7        // m-tiles of 16 rows
#define NPART 64      // key partials per (b,h): 16 chunks * 4 waves
// 1/sqrt(32) * log2(e)  (exp(x) == exp2(x*log2e), folded into q-scale)
#define SCALE2 0.2550602534365564f

typedef short bf16x8 __attribute__((ext_vector_type(8)));
typedef float f32x4  __attribute__((ext_vector_type(4)));
typedef unsigned short u16;
typedef unsigned int   u32;
typedef unsigned long long u64;

__device__ __forceinline__ u16 f2bf(float f) {          // RNE
  u32 u = __builtin_bit_cast(u32, f);
  u += 0x7fffu + ((u >> 16) & 1u);
  return (u16)(u >> 16);
}
__device__ __forceinline__ u16 f2bf_ru(float f) {       // round-half-up (2 VALU)
  return (u16)((__builtin_bit_cast(u32, f) + 0x8000u) >> 16);
}
// pack two fp32 -> bf16x2 (round-half-up), 3 VALU via v_perm
__device__ __forceinline__ u32 pack2rn(float lo, float hi) {
  u32 a = __builtin_bit_cast(u32, lo) + 0x8000u;
  u32 b = __builtin_bit_cast(u32, hi) + 0x8000u;
  return __builtin_amdgcn_perm(b, a, 0x07060302u);
}
__device__ __forceinline__ float bf_lo(u32 u) {
  return __builtin_bit_cast(float, u << 16);
}
__device__ __forceinline__ float bf_hi(u32 u) {
  return __builtin_bit_cast(float, u & 0xffff0000u);
}
__device__ __forceinline__ float fast_exp2(float x) {
#if __has_builtin(__builtin_amdgcn_exp2f)
  return __builtin_amdgcn_exp2f(x);
#else
  return exp2f(x);
#endif
}

// ---------------------------------------------------------------------------
// Kernel 1: q projection (scale*log2e folded in) + wconv side-work on the
// first 128 blocks (writes bf16 W_kv used by the NEXT dispatch).
// ---------------------------------------------------------------------------
__global__ __launch_bounds__(256) void proj_q_kernel(
    const float* __restrict__ query, const float* __restrict__ W,
    const float* __restrict__ bias, u16* __restrict__ q_bf,
    u16* __restrict__ wbf) {
  __shared__ float xrow[DM];
  const int bq = blockIdx.x;
  const int tid = threadIdx.x;
  if (bq < 128) {   // wconv: 131072 elems, 4/thread
    const int i = (bq * 256 + tid) * 4;
    const float4 w = *(const float4*)(W + 256 * DM + i);
    u32* dst = (u32*)(wbf + i);
    dst[0] = pack2rn(w.x, w.y);
    dst[1] = pack2rn(w.z, w.w);
  }
  const int b = bq / QQ, qi = bq % QQ;
  if (tid < 64)
    ((float4*)xrow)[tid] = ((const float4*)(query + (size_t)bq * DM))[tid];
  __syncthreads();
  const int j = tid;
  float acc = bias[j];
  const float4* wr = (const float4*)(W + (size_t)j * DM);
  #pragma unroll 8
  for (int c = 0; c < 64; ++c) {
    float4 w = wr[c];
    float4 x = ((const float4*)xrow)[c];
    acc += w.x * x.x + w.y * x.y + w.z * x.z + w.w * x.w;
  }
  acc *= SCALE2;
  const int h = j >> 5, d = j & 31;
  q_bf[(((size_t)(b * NH + h)) * QQ + qi) * HD + d] = f2bf(acc);
}

// ---------------------------------------------------------------------------
// Kernel 2: K/V projection GEMM. BM=32 keys/block (4096 blocks), barrier-free.
// Wave tile 32 keys x 128 cols (16 f32x4 acc = 64 VGPR -> 4 waves/SIMD via
// launch_bounds). Register double-buffer: next-ks A fp32 loads issued before
// current-ks pack+MFMA -> HBM latency covered. B-frags from bf16 weights
// (L2-hot, same addresses for all blocks). Epilogue via per-wave LDS:
// K as (b,h,key,d); V transposed as (b,h,d,key), dwordx4 stores.
// ---------------------------------------------------------------------------
__global__ __launch_bounds__(256, 4) void proj_kv_kernel(
    const float* __restrict__ kv, const u16* __restrict__ wbf,
    const float* __restrict__ bias, u16* __restrict__ k_bf,
    u16* __restrict__ v_t) {
  __shared__ u16 Tl[4][5120];
  const int rb = blockIdx.x;                 // 4096 blocks of 32 keys
  const size_t m0 = (size_t)rb * 32;
  const int tid = threadIdx.x, lane = tid & 63, wid = tid >> 6;
  const int lane15 = lane & 15, quad = lane >> 4;
  const int jw = wid * 128;                  // col base within 512

  f32x4 acc[2][8];
  #pragma unroll
  for (int mi = 0; mi < 2; ++mi)
    #pragma unroll
    for (int ni = 0; ni < 8; ++ni) acc[mi][ni] = (f32x4){0.f, 0.f, 0.f, 0.f};

  const float* abase = kv + (m0 + lane15) * DM + quad * 8;
  float4 a_cur[2][2], a_nxt[2][2];
  #pragma unroll
  for (int mi = 0; mi < 2; ++mi) {
    a_cur[mi][0] = ((const float4*)(abase + mi * 16 * DM))[0];
    a_cur[mi][1] = ((const float4*)(abase + mi * 16 * DM))[1];
  }

  for (int ks = 0; ks < 8; ++ks) {
    // prefetch next ks A slice (HBM) before consuming current
    #pragma unroll
    for (int mi = 0; mi < 2; ++mi) {
      a_nxt[mi][0] = a_cur[mi][0];
      a_nxt[mi][1] = a_cur[mi][1];
    }
    if (ks < 7) {
      #pragma unroll
      for (int mi = 0; mi < 2; ++mi) {
        const float* ap = abase + mi * 16 * DM + (ks + 1) * 32;
        a_nxt[mi][0] = ((const float4*)ap)[0];
        a_nxt[mi][1] = ((const float4*)ap)[1];
      }
    }
    bf16x8 afr[2];
    #pragma unroll
    for (int mi = 0; mi < 2; ++mi) {
      uint4 w;
      w.x = pack2rn(a_cur[mi][0].x, a_cur[mi][0].y);
      w.y = pack2rn(a_cur[mi][0].z, a_cur[mi][0].w);
      w.z = pack2rn(a_cur[mi][1].x, a_cur[mi][1].y);
      w.w = pack2rn(a_cur[mi][1].z, a_cur[mi][1].w);
      afr[mi] = __builtin_bit_cast(bf16x8, w);
    }
    #pragma unroll
    for (int ni = 0; ni < 8; ++ni) {
      bf16x8 bfr = __builtin_bit_cast(bf16x8,
          *(const uint4*)(wbf + (size_t)(jw + ni * 16 + lane15) * DM + ks * 32 + quad * 8));
      #pragma unroll
      for (int mi = 0; mi < 2; ++mi)
        acc[mi][ni] = __builtin_amdgcn_mfma_f32_16x16x32_bf16(afr[mi], bfr, acc[mi][ni], 0, 0, 0);
    }
    #pragma unroll
    for (int mi = 0; mi < 2; ++mi) {
      a_cur[mi][0] = a_nxt[mi][0];
      a_cur[mi][1] = a_nxt[mi][1];
    }
  }

  u16* T = Tl[wid];
  const float* bptr = bias + 256 + jw;
  if (wid < 2) {
    // ---- K: row(key)-major tile [32][136], coalesced (b,h,key,d) stores
    #pragma unroll
    for (int mi = 0; mi < 2; ++mi) {
      #pragma unroll
      for (int ni = 0; ni < 8; ++ni) {
        const float bv = bptr[ni * 16 + lane15];
        #pragma unroll
        for (int r = 0; r < 4; ++r)
          T[(mi * 16 + quad * 4 + r) * 136 + ni * 16 + lane15] =
              f2bf_ru(acc[mi][ni][r] + bv);
      }
    }
    #pragma unroll
    for (int it = 0; it < 8; ++it) {
      const int row = it * 4 + quad;          // 0..31
      const int c0 = lane15 * 8;              // 0..120
      uint4 val = *(const uint4*)&T[row * 136 + c0];
      const size_t m = m0 + row;
      const size_t b = m >> 14, key = m & 16383;
      const int col256 = jw + c0;             // 0..255 within K
      const int h = col256 >> 5, d = col256 & 31;
      *(uint4*)&k_bf[((b * NH + h) * HWK + key) * HD + d] = val;
    }
  } else {
    // ---- V: col(dim)-major tile [128][40] (key contiguous), (b,h,d,key)
    const int jwv = jw - 256;                 // 0 or 128 within V
    #pragma unroll
    for (int mi = 0; mi < 2; ++mi) {
      #pragma unroll
      for (int ni = 0; ni < 8; ++ni) {
        const float bv = bptr[ni * 16 + lane15];
        u32* dst = (u32*)&T[(ni * 16 + lane15) * 40 + mi * 16 + quad * 4];
        dst[0] = pack2rn(acc[mi][ni][0] + bv, acc[mi][ni][1] + bv);
        dst[1] = pack2rn(acc[mi][ni][2] + bv, acc[mi][ni][3] + bv);
      }
    }
    #pragma unroll
    for (int it = 0; it < 8; ++it) {
      const int col = it * 16 + (lane >> 2);  // 0..127
      const int koff = (lane & 3) * 8;        // 0..24
      uint4 val = *(const uint4*)&T[col * 40 + koff];
      const size_t m = m0 + koff;
      const size_t b = m >> 14, key = m & 16383;
      const int col256 = jwv + col;           // 0..255 within V
      const int h = col256 >> 5, d = col256 & 31;
      *(uint4*)&v_t[((b * NH + h) * HD + d) * HWK + key] = val;
    }
  }
}

// ---------------------------------------------------------------------------
// Kernel 3: chunked attention, software-pipelined. K/V uint4s for kg+1
// prefetched into registers before the 7-mt compute of kg; mask words for
// the whole kg batched from LDS upfront; staging loop 2-deep pipelined.
// Transposed score path (no LDS in hot loop), exp2 no-max softmax.
// ---------------------------------------------------------------------------
__global__ __launch_bounds__(256, 3) void attn_kernel(
    const u16* __restrict__ q_bf, const u16* __restrict__ k_bf,
    const u16* __restrict__ v_t, const int* __restrict__ mask,
    float* __restrict__ l_p, u32* __restrict__ ctxp) {
  __shared__ u16 qlds[QP * 40];
  __shared__ u32 mbitsw[QP * 33];      // [row][33 words], stride 33 = no conflicts
  const int tid = threadIdx.x;
  const int lane = tid & 63, wid = tid >> 6;
  const int lane15 = lane & 15, quad = lane >> 4;
  const int bh = blockIdx.x >> 4, chunk = blockIdx.x & 15;

  for (int i = tid; i < QP * HD; i += 256) {
    const int row = i >> 5, d = i & 31;
    qlds[row * 40 + d] = (row < QQ) ? q_bf[((size_t)bh * QQ + row) * HD + d] : (u16)0;
  }
  // ballot-compress mask slice, 2-deep row pipeline: wave w -> rows [25w,25w+25)
  {
    const int* mp_base = mask + (size_t)bh * QQ * HWK + chunk * 1024
                         + (size_t)(wid * 25) * HWK;
    int cur[16], nxt[16];
    #pragma unroll
    for (int g = 0; g < 16; ++g) cur[g] = mp_base[g * 64 + lane];
    for (int rr = 0; rr < 25; ++rr) {
      if (rr < 24) {
        const int* mp = mp_base + (size_t)(rr + 1) * HWK;
        #pragma unroll
        for (int g = 0; g < 16; ++g) nxt[g] = mp[g * 64 + lane];
      }
      u32 myw = 0;
      #pragma unroll
      for (int g = 0; g < 16; ++g) {
        const u64 bl = __ballot(cur[g] != 0);
        if (lane == 2 * g)     myw = (u32)bl;
        if (lane == 2 * g + 1) myw = (u32)(bl >> 32);
      }
      if (lane < 32) mbitsw[(wid * 25 + rr) * 33 + lane] = myw;
      #pragma unroll
      for (int g = 0; g < 16; ++g) cur[g] = nxt[g];
    }
  }
  __syncthreads();

  const int klocal_base = wid * 256;
  const int key_base = chunk * 1024 + klocal_base;
  const u16* kbase = k_bf + (size_t)bh * HWK * HD;
  const u16* vtb  = v_t  + (size_t)bh * HWK * HD;

  // cross-quad shuffle constants for the P^T relay
  const int sl_lo = lane15 + 32 * (quad & 1);
  const int sl_hi = sl_lo + 16;
  const u32 selperm = (quad & 2) ? 0x07060302u : 0x05040100u;  // hi : lo halves

  f32x4 acc[MT][2];
  float l_run[MT];
  #pragma unroll
  for (int mt = 0; mt < MT; ++mt) {
    acc[mt][0] = (f32x4){0.f, 0.f, 0.f, 0.f};
    acc[mt][1] = (f32x4){0.f, 0.f, 0.f, 0.f};
    l_run[mt] = 0.f;
  }

  // prefetch kg=0 K/V fragments
  uint4 kr0 = *(const uint4*)(kbase + (size_t)(key_base + lane15) * HD + quad * 8);
  uint4 kr1 = *(const uint4*)(kbase + (size_t)(key_base + 16 + lane15) * HD + quad * 8);
  uint4 vr0 = *(const uint4*)(vtb + (size_t)lane15 * HWK + key_base + quad * 8);
  uint4 vr1 = *(const uint4*)(vtb + (size_t)(lane15 + 16) * HWK + key_base + quad * 8);

  for (int kg = 0; kg < 8; ++kg) {
    // issue kg+1 loads first; latency covered by the 7-mt compute below
    uint4 nk0 = kr0, nk1 = kr1, nv0 = vr0, nv1 = vr1;
    if (kg < 7) {
      const int key0n = key_base + (kg + 1) * 32;
      nk0 = *(const uint4*)(kbase + (size_t)(key0n + lane15) * HD + quad * 8);
      nk1 = *(const uint4*)(kbase + (size_t)(key0n + 16 + lane15) * HD + quad * 8);
      nv0 = *(const uint4*)(vtb + (size_t)lane15 * HWK + key0n + quad * 8);
      nv1 = *(const uint4*)(vtb + (size_t)(lane15 + 16) * HWK + key0n + quad * 8);
    }
    // batch this kg's mask words (conflict-free LDS reads)
    const int widx = wid * 8 + kg;
    u32 wm[MT];
    #pragma unroll
    for (int mt = 0; mt < MT; ++mt) {
      const int rowg = mt * 16 + lane15;
      wm[mt] = mbitsw[rowg * 33 + widx];
      if (rowg >= QQ) wm[mt] = 0u;
    }
    bf16x8 kf0 = __builtin_bit_cast(bf16x8, kr0);
    bf16x8 kf1 = __builtin_bit_cast(bf16x8, kr1);
    bf16x8 vf0 = __builtin_bit_cast(bf16x8, vr0);
    bf16x8 vf1 = __builtin_bit_cast(bf16x8, vr1);
    #pragma unroll
    for (int mt = 0; mt < MT; ++mt) {
      bf16x8 af = __builtin_bit_cast(bf16x8,
          *(const uint4*)&qlds[(mt * 16 + lane15) * 40 + quad * 8]);
      const f32x4 zero = {0.f, 0.f, 0.f, 0.f};
      // S^T: m=key(quad*4+r), n=qrow(lane15)
      f32x4 s0 = __builtin_amdgcn_mfma_f32_16x16x32_bf16(kf0, af, zero, 0, 0, 0);
      f32x4 s1 = __builtin_amdgcn_mfma_f32_16x16x32_bf16(kf1, af, zero, 0, 0, 0);
      const u32 word = wm[mt];
      u32 pk[4];
      float lsum = 0.f;
      #pragma unroll
      for (int r = 0; r < 4; ++r) {
        const int kl = quad * 4 + r;
        const float p0 = ((word >> kl) & 1u)        ? fast_exp2(s0[r]) : 0.f;
        const float p1 = ((word >> (kl + 16)) & 1u) ? fast_exp2(s1[r]) : 0.f;
        lsum += p0 + p1;
        pk[r] = pack2rn(p0, p1);   // lo = key kl, hi = key kl+16
      }
      l_run[mt] += lsum;
      // relay P^T into B-operand layout: lane needs keys 8*quad + j
      u32 wA0 = (u32)__shfl((int)pk[0], sl_lo);
      u32 wA1 = (u32)__shfl((int)pk[1], sl_lo);
      u32 wA2 = (u32)__shfl((int)pk[2], sl_lo);
      u32 wA3 = (u32)__shfl((int)pk[3], sl_lo);
      u32 wB0 = (u32)__shfl((int)pk[0], sl_hi);
      u32 wB1 = (u32)__shfl((int)pk[1], sl_hi);
      u32 wB2 = (u32)__shfl((int)pk[2], sl_hi);
      u32 wB3 = (u32)__shfl((int)pk[3], sl_hi);
      uint4 pw;
      pw.x = __builtin_amdgcn_perm(wA1, wA0, selperm);
      pw.y = __builtin_amdgcn_perm(wA3, wA2, selperm);
      pw.z = __builtin_amdgcn_perm(wB1, wB0, selperm);
      pw.w = __builtin_amdgcn_perm(wB3, wB2, selperm);
      bf16x8 pf = __builtin_bit_cast(bf16x8, pw);
      // ctx^T: m=dim, n=qrow
      acc[mt][0] = __builtin_amdgcn_mfma_f32_16x16x32_bf16(vf0, pf, acc[mt][0], 0, 0, 0);
      acc[mt][1] = __builtin_amdgcn_mfma_f32_16x16x32_bf16(vf1, pf, acc[mt][1], 0, 0, 0);
    }
    kr0 = nk0; kr1 = nk1; vr0 = nv0; vr1 = nv1;
  }

  const int part = chunk * 4 + wid;
  #pragma unroll
  for (int mt = 0; mt < MT; ++mt) {
    const int row = mt * 16 + lane15;               // qrow (rows >= 100 junk, never read)
    float lr = l_run[mt];
    lr += __shfl_xor(lr, 16);
    lr += __shfl_xor(lr, 32);
    const size_t base = ((size_t)bh * QP + row) * NPART + part;
    if (quad == 0) l_p[base] = lr;
    uint2 lo2, hi2;
    lo2.x = pack2rn(acc[mt][0][0], acc[mt][0][1]);
    lo2.y = pack2rn(acc[mt][0][2], acc[mt][0][3]);
    hi2.x = pack2rn(acc[mt][1][0], acc[mt][1][1]);
    hi2.y = pack2rn(acc[mt][1][2], acc[mt][1][3]);
    *(uint2*)&ctxp[base * 16 + quad * 2]     = lo2;  // dims 4q..4q+3
    *(uint2*)&ctxp[base * 16 + 8 + quad * 2] = hi2;  // dims 16+4q..16+4q+3
  }
}

// ---------------------------------------------------------------------------
// Kernel 4: combine partials (bf16-packed ctx) + out-proj + residual + LN.
// ---------------------------------------------------------------------------
__global__ __launch_bounds__(256) void combine_kernel(
    const float* __restrict__ l_p, const u32* __restrict__ ctxp,
    const float* __restrict__ query, const float* __restrict__ Wo,
    const float* __restrict__ bo, const float* __restrict__ lnw,
    const float* __restrict__ lnb, float* __restrict__ out) {
  __shared__ float ctx_row[DM];
  __shared__ float red[8];
  const int bq = blockIdx.x;
  const int b = bq / QQ, qi = bq % QQ;
  const int tid = threadIdx.x, lane = tid & 63, wid = tid >> 6;

  for (int hh = 0; hh < 2; ++hh) {
    const int h = wid * 2 + hh;
    const size_t base = ((size_t)(b * NH + h) * QP + qi) * NPART;
    float lv = l_p[base + lane];
    #pragma unroll
    for (int o = 1; o < 64; o <<= 1) lv += __shfl_xor(lv, o);
    const float inv_l = 1.0f / lv;
    const int c = lane & 7, pg = lane >> 3;
    const u32* cp = ctxp + base * 16 + c * 2;
    float s0 = 0.f, s1 = 0.f, s2 = 0.f, s3 = 0.f;
    for (int p = pg; p < NPART; p += 8) {
      uint2 u = *(const uint2*)(cp + (size_t)p * 16);
      s0 += bf_lo(u.x); s1 += bf_hi(u.x);
      s2 += bf_lo(u.y); s3 += bf_hi(u.y);
    }
    #pragma unroll
    for (int o = 8; o < 64; o <<= 1) {
      s0 += __shfl_xor(s0, o);
      s1 += __shfl_xor(s1, o);
      s2 += __shfl_xor(s2, o);
      s3 += __shfl_xor(s3, o);
    }
    if (pg == 0) {
      ctx_row[h * HD + c * 4]     = s0 * inv_l;
      ctx_row[h * HD + c * 4 + 1] = s1 * inv_l;
      ctx_row[h * HD + c * 4 + 2] = s2 * inv_l;
      ctx_row[h * HD + c * 4 + 3] = s3 * inv_l;
    }
  }
  __syncthreads();

  const int j = tid;
  float s = bo[j];
  const float4* wr = (const float4*)(Wo + (size_t)j * DM);
  #pragma unroll 8
  for (int c = 0; c < 64; ++c) {
    float4 wv = wr[c];
    float4 cx = ((const float4*)ctx_row)[c];
    s += wv.x * cx.x + wv.y * cx.y + wv.z * cx.z + wv.w * cx.w;
  }
  const float x = s + query[(size_t)bq * DM + j];

  float t = x;
  #pragma unroll
  for (int o = 1; o < 64; o <<= 1) t += __shfl_xor(t, o);
  if (lane == 0) red[wid] = t;
  __syncthreads();
  const float mu = (red[0] + red[1] + red[2] + red[3]) * (1.0f / DM);
  const float dx = x - mu;
  float t2 = dx * dx;
  #pragma unroll
  for (int o = 1; o < 64; o <<= 1) t2 += __shfl_xor(t2, o);
  if (lane == 0) red[4 + wid] = t2;
  __syncthreads();
  const float var = (red[4] + red[5] + red[6] + red[7]) * (1.0f / DM);
  out[(size_t)bq * DM + j] = dx * rsqrtf(var + 1e-5f) * lnw[j] + lnb[j];
}

// ---------------------------------------------------------------------------
extern "C" void kernel_launch(void* const* d_in, const int* in_sizes, int n_in,
                              void* d_out, int out_size, void* d_ws, size_t ws_size,
                              hipStream_t stream) {
  const float* query = (const float*)d_in[0];
  const float* kv    = (const float*)d_in[1];
  const int*   mask  = (const int*)d_in[2];
  const float* ipw   = (const float*)d_in[3];
  const float* ipb   = (const float*)d_in[4];
  const float* opw   = (const float*)d_in[5];
  const float* opb   = (const float*)d_in[6];
  const float* lnw   = (const float*)d_in[7];
  const float* lnb   = (const float*)d_in[8];
  float* out = (float*)d_out;

  char* ws = (char*)d_ws;
  // ws: k 64MiB | v_t 64MiB | q 0.5MiB | l_p 1.75MiB | ctxp 28.7MiB | wbf 0.25MiB
  u16*   k_bf  = (u16*)(ws);
  u16*   v_t   = (u16*)(ws + 67108864);
  u16*   q_bf  = (u16*)(ws + 134217728);
  float* l_p   = (float*)(ws + 134742016);
  u32*   ctxp  = (u32*)(ws + 136577024);
  u16*   wbf   = (u16*)(ws + 195297280);

  proj_q_kernel <<<BB * QQ,      256, 0, stream>>>(query, ipw, ipb, q_bf, wbf);
  proj_kv_kernel<<<4096,         256, 0, stream>>>(kv, wbf, ipb, k_bf, v_t);
  attn_kernel   <<<BB * NH * 16, 256, 0, stream>>>(q_bf, k_bf, v_t, mask, l_p, ctxp);
  combine_kernel<<<BB * QQ,      256, 0, stream>>>(l_p, ctxp, query, opw, opb, lnw, lnb, out);
}